// Round 1
// baseline (59.629 us; speedup 1.0000x reference)
//
#include <hip/hip_runtime.h>
#include <hip/hip_bf16.h>

// DenseFastGAT: B=2, N=4096, IN=OUT=256, sparse (~1%) adjacency given dense.
//   K1: z = x @ W^T + bW            (bf16 MFMA GEMM, z fp32 -> d_out as scratch)
//   K2: ai/aj row dots + z->bf16    (wave per row)
//   K3: sparse attention            (block per row: compact edges, softmax, gather)

#define NNODES 4096
#define OUTF 256
#define INF 256

typedef __attribute__((ext_vector_type(8))) short short8v;
typedef __attribute__((ext_vector_type(4))) float f32x4;

__device__ __forceinline__ unsigned short f2bf(float f) {
    union { float f; unsigned u; } v; v.f = f;
    unsigned r = v.u + 0x7fffu + ((v.u >> 16) & 1u);   // RNE (finite inputs)
    return (unsigned short)(r >> 16);
}
__device__ __forceinline__ float bf2f(unsigned short u) {
    union { unsigned u; float f; } v; v.u = ((unsigned)u) << 16; return v.f;
}

// ---------------------------------------------------------------- K1: z GEMM
// M=8192, N=256, K=256. BM=128, BN=64, BK=64, 4 waves (2x2), 16x16x32 bf16 MFMA.
#define BM 128
#define BN 64
#define BK 64

__global__ __launch_bounds__(256) void zgemm_kernel(
        const float* __restrict__ x, const float* __restrict__ W,
        const float* __restrict__ bW, float* __restrict__ z) {
    __shared__ alignas(16) unsigned short As[BM * BK];  // [row][k], XOR-swizzled
    __shared__ alignas(16) unsigned short Bs[BN * BK];
    const int tid  = threadIdx.x;
    const int lane = tid & 63;
    const int wid  = tid >> 6;
    const int rowBase = blockIdx.x * BM;
    const int colBase = blockIdx.y * BN;
    const int wm = (wid >> 1) * 64;   // wave M offset
    const int wn = (wid & 1) * 32;    // wave N offset
    const int sr = tid >> 4;          // staging row 0..15
    const int sc = tid & 15;          // staging col-quad

    f32x4 acc[4][2] = {};

    for (int kk = 0; kk < INF; kk += BK) {
        // stage A (BM x BK) fp32 -> bf16, row stride 128B, byte ^= ((row&7)<<4)
        #pragma unroll
        for (int pass = 0; pass < BM / 16; ++pass) {
            int r = pass * 16 + sr;
            const float4 v = *(const float4*)(&x[(size_t)(rowBase + r) * INF + kk + sc * 4]);
            int off = r * 128 + ((sc * 8) ^ ((r & 7) << 4));
            *(ushort4*)((char*)As + off) =
                make_ushort4(f2bf(v.x), f2bf(v.y), f2bf(v.z), f2bf(v.w));
        }
        // stage B (BN x BK) from W[out][in]
        #pragma unroll
        for (int pass = 0; pass < BN / 16; ++pass) {
            int r = pass * 16 + sr;
            const float4 v = *(const float4*)(&W[(size_t)(colBase + r) * INF + kk + sc * 4]);
            int off = r * 128 + ((sc * 8) ^ ((r & 7) << 4));
            *(ushort4*)((char*)Bs + off) =
                make_ushort4(f2bf(v.x), f2bf(v.y), f2bf(v.z), f2bf(v.w));
        }
        __syncthreads();
        #pragma unroll
        for (int ks = 0; ks < 2; ++ks) {       // two K=32 sub-steps
            short8v aF[4], bF[2];
            #pragma unroll
            for (int m = 0; m < 4; ++m) {
                int row = wm + m * 16 + (lane & 15);
                int cb  = (ks * 64 + ((lane >> 4) * 16)) ^ ((row & 7) << 4);
                aF[m] = *(const short8v*)((const char*)As + row * 128 + cb);
            }
            #pragma unroll
            for (int n = 0; n < 2; ++n) {
                int row = wn + n * 16 + (lane & 15);
                int cb  = (ks * 64 + ((lane >> 4) * 16)) ^ ((row & 7) << 4);
                bF[n] = *(const short8v*)((const char*)Bs + row * 128 + cb);
            }
            #pragma unroll
            for (int m = 0; m < 4; ++m)
                #pragma unroll
                for (int n = 0; n < 2; ++n)
                    acc[m][n] = __builtin_amdgcn_mfma_f32_16x16x32_bf16(
                        aF[m], bF[n], acc[m][n], 0, 0, 0);
        }
        __syncthreads();
    }
    // epilogue: C/D layout col=lane&15, row=(lane>>4)*4+reg
    const int r4 = (lane >> 4) * 4;
    const int cW = lane & 15;
    #pragma unroll
    for (int n = 0; n < 2; ++n) {
        int col = colBase + wn + n * 16 + cW;
        float bias = bW[col];
        #pragma unroll
        for (int m = 0; m < 4; ++m) {
            int row0 = rowBase + wm + m * 16 + r4;
            #pragma unroll
            for (int r = 0; r < 4; ++r)
                z[(size_t)(row0 + r) * OUTF + col] = acc[m][n][r] + bias;
        }
    }
}

// ------------------------------------------- K2: ai/aj row dots + z -> bf16
__global__ __launch_bounds__(256) void rowvec_kernel(
        const float* __restrict__ z, const float* __restrict__ wai,
        const float* __restrict__ bai, const float* __restrict__ waj,
        const float* __restrict__ baj, unsigned short* __restrict__ zb,
        float* __restrict__ ai, float* __restrict__ aj) {
    const int lane = threadIdx.x & 63;
    const int wid  = threadIdx.x >> 6;
    const int row  = blockIdx.x * 4 + wid;          // 8192 rows / 4 per block
    const float4 v  = *(const float4*)(&z[(size_t)row * OUTF + lane * 4]);
    const float4 wi = *(const float4*)(&wai[lane * 4]);
    const float4 wj = *(const float4*)(&waj[lane * 4]);
    float si = v.x * wi.x + v.y * wi.y + v.z * wi.z + v.w * wi.w;
    float sj = v.x * wj.x + v.y * wj.y + v.z * wj.z + v.w * wj.w;
    *(ushort4*)(&zb[(size_t)row * OUTF + lane * 4]) =
        make_ushort4(f2bf(v.x), f2bf(v.y), f2bf(v.z), f2bf(v.w));
    #pragma unroll
    for (int off = 32; off; off >>= 1) {
        si += __shfl_down(si, off);
        sj += __shfl_down(sj, off);
    }
    if (lane == 0) { ai[row] = si + bai[0]; aj[row] = sj + baj[0]; }
}

// ---------------------------------------------------- K3: sparse attention
// One 256-thread block per (b,i) row. Deterministic sorted edge compaction
// via ballot prefix-scan; leaky is monotone so max_e = leaky(ai + max aj).
// Masked (-9e15) and sink (-1e9) terms underflow to exactly 0 for rows with
// edges; rows without edges output exactly 0 (matches reference).
#define CAP 4096
__global__ __launch_bounds__(256) void attn_kernel(
        const float* __restrict__ adj, const unsigned short* __restrict__ zb,
        const float* __restrict__ ai_arr, const float* __restrict__ aj_arr,
        float* __restrict__ out) {
    __shared__ unsigned short s_idx[CAP];
    __shared__ float s_w[CAP];
    __shared__ int   s_wsum[4];
    __shared__ float s_red[4];
    __shared__ int   s_cnt;
    const int tid  = threadIdx.x;
    const int lane = tid & 63;
    const int wid  = tid >> 6;
    const int row  = blockIdx.x;          // 0..8191
    const int b    = row >> 12;
    const float4* arow = (const float4*)(adj + (size_t)row * NNODES);

    if (tid == 0) s_cnt = 0;
    float4 v[4];
    #pragma unroll
    for (int t = 0; t < 4; ++t) v[t] = arow[t * 256 + tid];   // whole 16KB row
    __syncthreads();

    #pragma unroll
    for (int t = 0; t < 4; ++t) {
        int pred = (v[t].x > 0.f ? 1 : 0) | (v[t].y > 0.f ? 2 : 0) |
                   (v[t].z > 0.f ? 4 : 0) | (v[t].w > 0.f ? 8 : 0);
        unsigned long long b0 = __ballot(pred & 1);
        unsigned long long b1 = __ballot((pred >> 1) & 1);
        unsigned long long b2 = __ballot((pred >> 2) & 1);
        unsigned long long b3 = __ballot((pred >> 3) & 1);
        int wtot = __popcll(b0) + __popcll(b1) + __popcll(b2) + __popcll(b3);
        if (lane == 0) s_wsum[wid] = wtot;
        __syncthreads();
        unsigned long long below = (1ull << lane) - 1ull;
        int pre = __popcll(b0 & below) + __popcll(b1 & below) +
                  __popcll(b2 & below) + __popcll(b3 & below);
        const int cnt0 = s_cnt;
        int base = cnt0, tot = 0;
        #pragma unroll
        for (int w = 0; w < 4; ++w) { int c = s_wsum[w]; if (w < wid) base += c; tot += c; }
        int pos = base + pre;
        int jb  = t * 1024 + tid * 4;
        if (pred & 1) s_idx[pos++] = (unsigned short)(jb);
        if (pred & 2) s_idx[pos++] = (unsigned short)(jb + 1);
        if (pred & 4) s_idx[pos++] = (unsigned short)(jb + 2);
        if (pred & 8) s_idx[pos++] = (unsigned short)(jb + 3);
        __syncthreads();
        if (tid == 0) s_cnt = cnt0 + tot;
    }
    __syncthreads();
    const int cnt = s_cnt;
    float* orow = out + (size_t)row * OUTF;
    if (cnt == 0) { orow[tid] = 0.f; return; }

    const float aival = ai_arr[row];
    const float* ajb = aj_arr + (b << 12);

    // pass 1: gather aj for edges (cache into s_w), block max
    float lm = -3e38f;
    for (int p = tid; p < cnt; p += 256) {
        float a = ajb[s_idx[p]];
        s_w[p] = a;
        lm = fmaxf(lm, a);
    }
    #pragma unroll
    for (int off = 32; off; off >>= 1) lm = fmaxf(lm, __shfl_down(lm, off));
    if (lane == 0) s_red[wid] = lm;
    __syncthreads();
    float mj = fmaxf(fmaxf(s_red[0], s_red[1]), fmaxf(s_red[2], s_red[3]));
    float tm = aival + mj;
    const float m = tm >= 0.f ? tm : 0.2f * tm;   // leaky is monotone
    __syncthreads();                              // protect s_red reuse

    // pass 2: weights + denominator
    float ls = 0.f;
    for (int p = tid; p < cnt; p += 256) {
        float e = aival + s_w[p];
        e = e >= 0.f ? e : 0.2f * e;
        float w = __expf(e - m);
        s_w[p] = w;
        ls += w;
    }
    #pragma unroll
    for (int off = 32; off; off >>= 1) ls += __shfl_down(ls, off);
    if (lane == 0) s_red[wid] = ls;
    __syncthreads();
    const float inv = 1.f / (s_red[0] + s_red[1] + s_red[2] + s_red[3]);

    // pass 3: out[:,tid] = sum_p w_p * z[j_p][tid] / denom
    const unsigned short* zbb = zb + ((size_t)(b << 12)) * OUTF;
    float acc = 0.f;
    int p = 0;
    for (; p + 4 <= cnt; p += 4) {
        int   j0 = s_idx[p],   j1 = s_idx[p + 1], j2 = s_idx[p + 2], j3 = s_idx[p + 3];
        float w0 = s_w[p],     w1 = s_w[p + 1],   w2 = s_w[p + 2],   w3 = s_w[p + 3];
        float z0 = bf2f(zbb[(size_t)j0 * OUTF + tid]);
        float z1 = bf2f(zbb[(size_t)j1 * OUTF + tid]);
        float z2 = bf2f(zbb[(size_t)j2 * OUTF + tid]);
        float z3 = bf2f(zbb[(size_t)j3 * OUTF + tid]);
        acc = fmaf(w0, z0, fmaf(w1, z1, fmaf(w2, z2, fmaf(w3, z3, acc))));
    }
    for (; p < cnt; ++p)
        acc = fmaf(s_w[p], bf2f(zbb[(size_t)s_idx[p] * OUTF + tid]), acc);
    orow[tid] = acc * inv;
}

extern "C" void kernel_launch(void* const* d_in, const int* in_sizes, int n_in,
                              void* d_out, int out_size, void* d_ws, size_t ws_size,
                              hipStream_t stream) {
    const float* x   = (const float*)d_in[0];
    const float* adj = (const float*)d_in[1];
    const float* W   = (const float*)d_in[2];
    const float* bW  = (const float*)d_in[3];
    const float* wai = (const float*)d_in[4];
    const float* bai = (const float*)d_in[5];
    const float* waj = (const float*)d_in[6];
    const float* baj = (const float*)d_in[7];
    float* out = (float*)d_out;

    float* z = out;                                   // fp32 z scratch in d_out
    unsigned short* zb = (unsigned short*)d_ws;       // 4 MB bf16 z
    float* ai = (float*)((char*)d_ws + (4u << 20));            // 32 KB
    float* aj = (float*)((char*)d_ws + (4u << 20) + 32768);    // 32 KB

    zgemm_kernel<<<dim3(8192 / BM, OUTF / BN), 256, 0, stream>>>(x, W, bW, z);
    rowvec_kernel<<<8192 / 4, 256, 0, stream>>>(z, wai, bai, waj, baj, zb, ai, aj);
    attn_kernel<<<8192, 256, 0, stream>>>(adj, zb, ai, aj, out);
}